// Round 9
// baseline (165.058 us; speedup 1.0000x reference)
//
#include <hip/hip_runtime.h>

#define PI_F 3.14159265358979f

typedef unsigned int  uint32;
typedef unsigned short ushort16;

// ---------------------------------------------------------------------------
// complex / bf16 helpers
// ---------------------------------------------------------------------------
__device__ __forceinline__ float2 cmul(float2 a, float2 b) {
    return make_float2(a.x * b.x - a.y * b.y, a.x * b.y + a.y * b.x);
}
__device__ __forceinline__ float2 cadd(float2 a, float2 b) { return make_float2(a.x + b.x, a.y + b.y); }
__device__ __forceinline__ float2 csub(float2 a, float2 b) { return make_float2(a.x - b.x, a.y - b.y); }
__device__ __forceinline__ float2 shflx(float2 v, int m) {
    return make_float2(__shfl_xor(v.x, m, 64), __shfl_xor(v.y, m, 64));
}
__device__ __forceinline__ float2 shfli(float2 v, int src) {
    return make_float2(__shfl(v.x, src, 64), __shfl(v.y, src, 64));
}
__device__ __forceinline__ int brev6(int x) { return (int)(__brev((unsigned)x) >> 26); }

__device__ __forceinline__ uint32 bfu(float x) {              // fp32 -> bf16 (RNE), low 16
    uint32 u = __float_as_uint(x);
    return (u + 0x7FFFu + ((u >> 16) & 1u)) >> 16;
}
__device__ __forceinline__ uint32 packbf2(float2 v) { return bfu(v.x) | (bfu(v.y) << 16); }
__device__ __forceinline__ float2 unpackbf2(uint32 u) {
    return make_float2(__uint_as_float(u << 16), __uint_as_float(u & 0xFFFF0000u));
}
__device__ __forceinline__ float bf2f(ushort16 u) { return __uint_as_float((uint32)u << 16); }

// DPP cross-lane exchange (no LDS pipe): xor1 = quad_perm[1,0,3,2] (0xB1),
// xor2 = quad_perm[2,3,0,1] (0x4E), xor8 = row_ror:8 (0x128).
template<int CTRL>
__device__ __forceinline__ float dpp1(float x) {
    return __builtin_bit_cast(float, __builtin_amdgcn_update_dpp(
        0, __builtin_bit_cast(int, x), CTRL, 0xF, 0xF, true));
}
template<int CTRL>
__device__ __forceinline__ float2 dppx(float2 v) {
    return make_float2(dpp1<CTRL>(v.x), dpp1<CTRL>(v.y));
}
template<int M>
__device__ __forceinline__ float2 xorx(float2 v) {
    if constexpr (M == 1)      return dppx<0xB1>(v);
    else if constexpr (M == 2) return dppx<0x4E>(v);
    else if constexpr (M == 8) return dppx<0x128>(v);
    else                       return shflx(v, M);
}

// Per-lane twiddles for the 6 shuffle DIF stages (m = 32,16,8,4,2,1).
template<bool INV>
__device__ __forceinline__ void tw_init(int lane, float2* w, float* sg) {
#pragma unroll
    for (int t = 0; t < 6; ++t) {
        int m = 32 >> t;
        bool up = (lane & m) != 0;
        int pos = lane & (m - 1);
        float ang = (INV ? PI_F : -PI_F) * (float)pos / (float)m;
        float sn, cs;
        __sincosf(ang, &sn, &cs);
        w[t]  = up ? make_float2(cs, sn) : make_float2(1.f, 0.f);
        sg[t] = up ? -1.f : 1.f;
    }
}

// 64-pt DIF FFT across the wave, 1 elem/lane. Natural in; out: lane l holds X[brev6(l)].
__device__ __forceinline__ float2 fft64s(float2 v, const float2* w, const float* sg) {
#define FFT_STAGE(T, M) { float2 p = xorx<M>(v);                                   \
        float2 d = make_float2(fmaf(sg[T], v.x, p.x), fmaf(sg[T], v.y, p.y));      \
        v = cmul(d, w[T]); }
    FFT_STAGE(0, 32) FFT_STAGE(1, 16) FFT_STAGE(2, 8)
    FFT_STAGE(3, 4)  FFT_STAGE(4, 2)  FFT_STAGE(5, 1)
#undef FFT_STAGE
    return v;
}

// ---------------------------------------------------------------------------
// kfft body (one block per (c1,c2) image): rfft2(128x128) in regs +
// frequency-domain D4 symmetrization -> real K (128 x 64) in bf16.
// ---------------------------------------------------------------------------
__device__ void kfft_body(const float* __restrict__ kin, ushort16* __restrict__ kout,
                          float2* X, int img) {
    int lane = threadIdx.x & 63, wv = threadIdx.x >> 6;   // 8 waves
    float2 w[6]; float sg[6];
    tw_init<false>(lane, w, sg);
    int b6 = brev6(lane);
    float sn, cs;
    __sincosf(-PI_F * (float)lane * (1.0f / 64.0f), &sn, &cs);
    float2 w64 = make_float2(cs, sn);           // col intra-stage twiddle (lane-based)
    __sincosf(-PI_F * (float)b6 * (1.0f / 64.0f), &sn, &cs);
    float2 wub = make_float2(cs, sn);           // rfft unpack twiddle at k = b6
    const float2* in2 = (const float2*)(kin + (size_t)img * 16384);
    int gm2 = brev6((64 - b6) & 63);            // lane holding Z[(64-b6)&63]
    // ---- row phase: 16 rows per wave, rfft128 via cfft64 in regs ----
#pragma unroll 2
    for (int rr = 0; rr < 16; ++rr) {
        int r = wv * 16 + rr;
        float2 z = in2[r * 64 + lane];
        z = fft64s(z, w, sg);                   // lane l holds Z[brev6(l)]
        float2 zm = shfli(z, gm2);
        float ar = z.x + zm.x, ai = z.y - zm.y;
        float br = z.x - zm.x, bi = z.y + zm.y;
        float p = wub.x * br - wub.y * bi, q = wub.x * bi + wub.y * br;
        X[r * 65 + b6] = make_float2(0.5f * (ar + q), 0.5f * (ai - p));
    }
    __syncthreads();
    // ---- col phase: 8 cols per wave, cfft128 (2 regs/lane) ----
    float2 c0[8], c1[8];
#pragma unroll
    for (int cc = 0; cc < 8; ++cc) {
        int k = wv * 8 + cc;
        c0[cc] = X[lane * 65 + k];
        c1[cc] = X[(lane + 64) * 65 + k];
    }
    __syncthreads();                            // all X reads done; reuse LDS as Rr
    float* Rr = (float*)X;
#pragma unroll
    for (int cc = 0; cc < 8; ++cc) {
        int k = wv * 8 + cc;
        float2 r0 = c0[cc], r1 = c1[cc];
        float2 t = r0;
        r0 = cadd(t, r1);
        r1 = cmul(csub(t, r1), w64);
        r0 = fft64s(r0, w, sg);
        r1 = fft64s(r1, w, sg);
        Rr[(2 * b6) * 65 + k]     = r0.x;
        Rr[(2 * b6 + 1) * 65 + k] = r1.x;
    }
    __syncthreads();
    // ---- frequency-domain D4 symmetrization (ushort4 bf16 stores) ----
    ushort4* ko4 = (ushort4*)(kout + (size_t)img * 8192);
    for (int i = threadIdx.x; i < 2048; i += 512) {
        int n = i >> 4, k4 = (i & 15) << 2;
        float op[4];
#pragma unroll
        for (int m = 0; m < 4; ++m) {
            int k = k4 + m;
            float t1 = Rr[n * 65 + k];
            float t2 = Rr[((128 - n) & 127) * 65 + k];
            float t3, t4;
            if (n < 64) {
                t3 = Rr[k * 65 + n];
                t4 = Rr[((128 - k) & 127) * 65 + n];
            } else {
                int c2 = 128 - n; if (c2 > 63) c2 = 63;   // n==64 unused downstream
                t3 = Rr[((128 - k) & 127) * 65 + c2];
                t4 = Rr[k * 65 + c2];
            }
            op[m] = 0.25f * (t1 + t2 + t3 + t4);
        }
        ushort4 o4;
        o4.x = (ushort16)bfu(op[0]); o4.y = (ushort16)bfu(op[1]);
        o4.z = (ushort16)bfu(op[2]); o4.w = (ushort16)bfu(op[3]);
        ko4[i] = o4;
    }
}

// ---------------------------------------------------------------------------
// ffull body (one block per (b,c1) f-image): 256 row rfft256s -> packed bf16
// spectrum in LDS (stride 65, odd => conflict-free col reads) -> col cfft256
// per column (in-place per col, no hazards) -> truncated/scaled FHAT.
// ---------------------------------------------------------------------------
__device__ void ffull_body(const float* __restrict__ f, uint32* __restrict__ FH,
                           uint32* A, int img) {
    int lane = threadIdx.x & 63, wv = threadIdx.x >> 6;   // 8 waves
    float2 w[6]; float sg[6];
    tw_init<false>(lane, w, sg);
    int m = brev6(lane);
    float sn, cs;
    __sincosf(-PI_F * (float)lane * (1.0f / 64.0f), &sn, &cs);
    float2 w64 = make_float2(cs, sn);
    __sincosf(-PI_F * (float)(2 * m) * (1.0f / 128.0f), &sn, &cs);
    float2 wue = make_float2(cs, sn);           // unpack twiddle, k = 2m
    __sincosf(-PI_F * (float)(2 * m + 1) * (1.0f / 128.0f), &sn, &cs);
    float2 wuo = make_float2(cs, sn);           // unpack twiddle, k = 2m+1
    int src_e = brev6((64 - m) & 63);           // lane holding Z[2*(64-m)] in r0
    int src_o = brev6(63 - m);                  // lane holding Z[2*(63-m)+1] in r1
    bool active = (lane & 1) == 0;              // m < 32
    const float2* base = (const float2*)(f + (size_t)img * 65536);
    // ---- row phase: 32 rows per wave ----
#pragma unroll 2
    for (int rr = 0; rr < 32; ++rr) {
        int r = wv * 32 + rr;
        float2 r0 = base[r * 128 + lane], r1 = base[r * 128 + 64 + lane];
        float2 t = r0;
        r0 = cadd(t, r1);
        r1 = cmul(csub(t, r1), w64);
        r0 = fft64s(r0, w, sg);                 // r0[l] = Z[2*brev6(l)]
        r1 = fft64s(r1, w, sg);                 // r1[l] = Z[2*brev6(l)+1]
        float2 zme = shfli(r0, src_e);          // Z[128-2m]
        float2 zmo = shfli(r1, src_o);          // Z[128-(2m+1)]
        float ar = r0.x + zme.x, ai = r0.y - zme.y;
        float br = r0.x - zme.x, bi = r0.y + zme.y;
        float p = wue.x * br - wue.y * bi, q = wue.x * bi + wue.y * br;
        uint32 xe = packbf2(make_float2(0.5f * (ar + q), 0.5f * (ai - p)));
        ar = r1.x + zmo.x; ai = r1.y - zmo.y;
        br = r1.x - zmo.x; bi = r1.y + zmo.y;
        p = wuo.x * br - wuo.y * bi; q = wuo.x * bi + wuo.y * br;
        uint32 xo = packbf2(make_float2(0.5f * (ar + q), 0.5f * (ai - p)));
        if (active) {
            A[r * 65 + 2 * m]     = xe;
            A[r * 65 + 2 * m + 1] = xo;
        }
    }
    __syncthreads();
    // ---- col phase: 8 cols per wave, cfft256 one col at a time (in place) ----
    __sincosf(-PI_F * (float)lane * (1.0f / 128.0f), &sn, &cs);
    float2 w128a = make_float2(cs, sn);
    __sincosf(-PI_F * (float)(lane + 64) * (1.0f / 128.0f), &sn, &cs);
    float2 w128b = make_float2(cs, sn);
    int b6 = brev6(lane);
#pragma unroll
    for (int cc = 0; cc < 8; ++cc) {
        int c = wv * 8 + cc;
        float2 r0 = unpackbf2(A[(lane)       * 65 + c]);
        float2 r1 = unpackbf2(A[(lane +  64) * 65 + c]);
        float2 r2 = unpackbf2(A[(lane + 128) * 65 + c]);
        float2 r3 = unpackbf2(A[(lane + 192) * 65 + c]);
        float2 t;
        t = r0; r0 = cadd(t, r2); r2 = cmul(csub(t, r2), w128a);
        t = r1; r1 = cadd(t, r3); r3 = cmul(csub(t, r3), w128b);
        t = r0; r0 = cadd(t, r1); r1 = cmul(csub(t, r1), w64);
        t = r2; r2 = cadd(t, r3); r3 = cmul(csub(t, r3), w64);
        r0 = fft64s(r0, w, sg); r1 = fft64s(r1, w, sg);
        r2 = fft64s(r2, w, sg); r3 = fft64s(r3, w, sg);
        float2 vv[4] = { r0, r2, r1, r3 };      // n = 4*b6 + j (brev2 order)
#pragma unroll
        for (int j = 0; j < 4; ++j) {
            int n = 4 * b6 + j;
            int r = (n < 64) ? n : ((n >= 193) ? n - 128 : -1);
            if (r >= 0)
                A[r * 65 + c] = packbf2(make_float2(vv[j].x * 0.25f, vv[j].y * 0.25f));
        }
    }
    __syncthreads();
    // ---- coalesced copy-out ----
    uint32* dst = FH + (size_t)img * 8192;
    for (int i = threadIdx.x; i < 8192; i += 512) {
        int r = i >> 6, c = i & 63;
        dst[i] = (r == 64) ? 0u : A[r * 65 + c];
    }
}

// ---------------------------------------------------------------------------
// L1: ffull (bid<128, fat blocks first) || kfft (bid>=128)
// ---------------------------------------------------------------------------
__global__ __launch_bounds__(512) void mega1(const float* __restrict__ kin,
                                             ushort16* __restrict__ Kr,
                                             const float* __restrict__ f,
                                             uint32* __restrict__ FH) {
    __shared__ uint32 SH[128 * 2 * 65];         // 66,560 B, shared by both bodies
    int bid = blockIdx.x;
    if (bid < 128) ffull_body(f, FH, SH, bid);
    else           kfft_body(kin, Kr, (float2*)SH, bid - 128);
}

// ---------------------------------------------------------------------------
// einsum body: C[b,d,nk] = sum_c F[b,c,nk] * K[c,d,nk] (K real bf16).
// One 32-nk group per block, 512 threads. F staged packed in LDS (16 KB).
// ---------------------------------------------------------------------------
__device__ void einsum_body(const uint32* __restrict__ F, const ushort16* __restrict__ K,
                            uint32* __restrict__ C, uint32* Ft, int bid) {
    int nk0 = bid * 32;
    int t = threadIdx.x;
    for (int i = t; i < 4096; i += 512) {
        int bc = i >> 5, nl = i & 31;
        Ft[i] = F[(size_t)bc * 8192 + nk0 + nl];
    }
    __syncthreads();
    int nl = t & 31, dg = t >> 5;               // dg 0..15
    int nk = nk0 + nl;
    float2 acc[2][8] = {};
#pragma unroll
    for (int c = 0; c < 16; ++c) {
        float2 fv[8];
#pragma unroll
        for (int b = 0; b < 8; ++b) fv[b] = unpackbf2(Ft[(b * 16 + c) * 32 + nl]);
#pragma unroll
        for (int j = 0; j < 2; ++j) {
            int d = j * 16 + dg;
            float kv = bf2f(K[(size_t)(c * 32 + d) * 8192 + nk]);
#pragma unroll
            for (int b = 0; b < 8; ++b) {
                acc[j][b].x = fmaf(fv[b].x, kv, acc[j][b].x);
                acc[j][b].y = fmaf(fv[b].y, kv, acc[j][b].y);
            }
        }
    }
#pragma unroll
    for (int j = 0; j < 2; ++j) {
        int d = j * 16 + dg;
#pragma unroll
        for (int b = 0; b < 8; ++b)
            C[(size_t)(b * 32 + d) * 8192 + nk] = packbf2(acc[j][b]);
    }
}

// ---------------------------------------------------------------------------
// ifuse body (one output image, bf16 input): col icfft128 in regs, row pack +
// icfft64 in regs -> 128x128 fp32 reals, scaled 1/8192.
// ---------------------------------------------------------------------------
__device__ void ifuse_body(const uint32* __restrict__ src, float2* __restrict__ dst,
                           float2* S) {
    int lane = threadIdx.x & 63, wv = threadIdx.x >> 6;   // 8 waves
    float2 w[6]; float sg[6];
    tw_init<true>(lane, w, sg);
    float sn, cs;
    __sincosf(PI_F * (float)lane * (1.0f / 64.0f), &sn, &cs);
    float2 w64 = make_float2(cs, sn);           // inverse intra-stage AND pack twiddle
    for (int i = threadIdx.x; i < 8192; i += 512) {
        int r = i >> 6, c = i & 63;
        S[r * 65 + c] = unpackbf2(src[i]);
    }
    __syncthreads();
    float2 c0[8], c1[8];
#pragma unroll
    for (int cc = 0; cc < 8; ++cc) {
        int k = wv * 8 + cc;
        c0[cc] = S[lane * 65 + k];
        c1[cc] = S[(lane + 64) * 65 + k];
    }
    __syncthreads();
    int b6 = brev6(lane);
#pragma unroll
    for (int cc = 0; cc < 8; ++cc) {
        int k = wv * 8 + cc;
        float2 r0 = c0[cc], r1 = c1[cc];
        float2 t = r0;
        r0 = cadd(t, r1);
        r1 = cmul(csub(t, r1), w64);
        r0 = fft64s(r0, w, sg);
        r1 = fft64s(r1, w, sg);
        S[(2 * b6) * 65 + k]     = r0;
        S[(2 * b6 + 1) * 65 + k] = r1;
    }
    __syncthreads();
    // ---- row phase: irfft128 via icfft64, 16 rows per wave ----
#pragma unroll 2
    for (int rr = 0; rr < 16; ++rr) {
        int m = wv * 16 + rr;
        float2 X = S[m * 65 + lane];
        float2 Xm = shfli(X, (64 - lane) & 63);
        if (lane == 0) Xm = make_float2(0.f, 0.f);   // X[64] == 0
        float er = 0.5f * (X.x + Xm.x), ei = 0.5f * (X.y - Xm.y);
        float br = 0.5f * (X.x - Xm.x), bi = 0.5f * (X.y + Xm.y);
        float orr = w64.x * br - w64.y * bi, oi = w64.x * bi + w64.y * br;
        float2 Z = make_float2(er - oi, ei + orr);
        Z = fft64s(Z, w, sg);                   // lane l holds z[brev6(l)]
        dst[m * 64 + b6] = make_float2(Z.x * (1.0f / 8192.0f), Z.y * (1.0f / 8192.0f));
    }
}

// ---------------------------------------------------------------------------
// L2: einsum (bid<256) || ifuse out0 (bid>=256);  L3: ifuse out1
// ---------------------------------------------------------------------------
__global__ __launch_bounds__(512) void mega2(const uint32* __restrict__ FH,
                                             const ushort16* __restrict__ Kr,
                                             uint32* __restrict__ CONV,
                                             float* __restrict__ out) {
    __shared__ float2 SH[128 * 65];
    int bid = blockIdx.x;
    if (bid < 256) einsum_body(FH, Kr, CONV, (uint32*)SH, bid);
    else {
        int img = bid - 256;                    // 0..127 -> out0
        ifuse_body(FH + (size_t)img * 8192, (float2*)(out + (size_t)img * 16384), SH);
    }
}

__global__ __launch_bounds__(512) void ifuse1(const uint32* __restrict__ CV,
                                              float* __restrict__ out1) {
    __shared__ float2 SH[128 * 65];
    int img = blockIdx.x;                       // 0..255 -> out1
    ifuse_body(CV + (size_t)img * 8192, (float2*)(out1 + (size_t)img * 16384), SH);
}

// ---------------------------------------------------------------------------
// Launch
// ---------------------------------------------------------------------------
extern "C" void kernel_launch(void* const* d_in, const int* in_sizes, int n_in,
                              void* d_out, int out_size, void* d_ws, size_t ws_size,
                              hipStream_t stream) {
    const float* f   = (const float*)d_in[0];   // (8,16,256,256)
    const float* kin = (const float*)d_in[1];   // (1,16,32,128,128)
    float* out = (float*)d_out;                 // (8,16,128,128) | (8,32,128,128)
    char* ws = (char*)d_ws;

    // workspace (bf16 intermediates):
    //   [0, 8388608)          : CONV (256 x 8192 bf16c)
    //   [8388608, 12582912)   : FHAT (128 x 8192 bf16c)
    //   [16777216, 25165824)  : Kr (512 x 8192 bf16)
    uint32*   CONV = (uint32*)ws;
    uint32*   FHAT = (uint32*)(ws + 8388608);
    ushort16* Kr   = (ushort16*)(ws + 16777216);

    mega1<<<640, 512, 0, stream>>>(kin, Kr, f, FHAT);        // ffull (128) || kfft (512)
    mega2<<<384, 512, 0, stream>>>(FHAT, Kr, CONV, out);     // einsum || ifuse out0
    ifuse1<<<256, 512, 0, stream>>>(CONV, out + 2097152);    // ifuse out1
}